// Round 6
// baseline (1494.383 us; speedup 1.0000x reference)
//
#include <hip/hip_runtime.h>
#include <math.h>

#define NR 131072
#define KC 1024
#define DD 256

// d_out element offsets (float32 elements)
#define ZQ_OFF  0
#define RES_OFF 33554432
#define IDX_OFF 67108864
#define LOSS_OFF 67239936
#define PERP_OFF 67239937

// ws byte offsets (total 40 KB)
#define WS_CNT 0        // int[1024]
#define WS_C2N 4096     // float[1024]
#define WS_BSS 8192     // double[4096]

#define FM(x,y) __fmul_rn((x),(y))
#define FA(x,y) __fadd_rn((x),(y))

// ---- numpy f32 pairwise sum of squares over 256 contiguous floats ----------
// Replicates np.sum(x*x, axis=-1) for n=256 on AVX512 numpy + gcc reduce:
//   pairwise split: 256 -> 128 + 128 (combined LAST)
//   per-128 block: 8 vector accumulators of 16 lanes:
//     lane[l] = ((a[l]^2 + a[16+l]^2) + (a[32+l]^2 + a[48+l]^2))
//             + ((a[64+l]^2 + a[80+l]^2) + (a[96+l]^2 + a[112+l]^2))
//   then _mm512_reduce_add_ps halving tree over lanes: bits 8,4,2,1.
// All ops via __fmul_rn/__fadd_rn to block FMA contraction/reassociation.
static __device__ __forceinline__ float np_sumsq256(const float* __restrict__ p) {
  float blk[2];
#pragma unroll
  for (int b = 0; b < 2; b++) {
    const float* q = p + b * 128;
    float lane[16];
#pragma unroll
    for (int l = 0; l < 16; l++) {
      float s0 = FM(q[l +   0], q[l +   0]);
      float s1 = FM(q[l +  16], q[l +  16]);
      float s2 = FM(q[l +  32], q[l +  32]);
      float s3 = FM(q[l +  48], q[l +  48]);
      float s4 = FM(q[l +  64], q[l +  64]);
      float s5 = FM(q[l +  80], q[l +  80]);
      float s6 = FM(q[l +  96], q[l +  96]);
      float s7 = FM(q[l + 112], q[l + 112]);
      lane[l] = FA(FA(FA(s0, s1), FA(s2, s3)), FA(FA(s4, s5), FA(s6, s7)));
    }
#pragma unroll
    for (int h = 8; h >= 1; h >>= 1)
#pragma unroll
      for (int l = 0; l < 8; l++)
        if (l < h) lane[l] = FA(lane[l], lane[l + h]);
    blk[b] = lane[0];
  }
  return FA(blk[0], blk[1]);
}

// ---------------- K1: codebook c2 (numpy-replica f32) -----------------------
__global__ void vq6_c2(const float* __restrict__ cb, float* __restrict__ c2n) {
  const int code = blockIdx.x * 256 + threadIdx.x;   // 4 blocks x 256
  if (code < KC) c2n[code] = np_sumsq256(cb + (size_t)code * DD);
}

// ---------------- K2: fused np-f32 argmin + gather + outputs ---------------
__global__ __launch_bounds__(256) void vq6_main(
    const float* __restrict__ z, const float* __restrict__ cb,
    const float* __restrict__ c2n,
    float* __restrict__ out, int* __restrict__ counts,
    double* __restrict__ bss) {
  __shared__ __align__(16) float zt[32 * 260];   // 33,280 B  z tile (padded)
  __shared__ __align__(16) float sc[2304];       //  9,216 B  code tile / reduce
  __shared__ float z2s[32];
  __shared__ int rowidx[32];
  __shared__ double wred[4];

  const int tid = threadIdx.x;
  const int wg  = blockIdx.x;     // 4096 blocks, 32 rows each
  const int tr  = tid >> 4;       // 0..15: rows {tr, tr+16}
  const int tc  = tid & 15;       // 0..15: codes ≡ tc (mod 16)

  // ---- stage z tile (32 x 256, padded stride 260) ----
  {
    const float4* zg = (const float4*)(z + (size_t)wg * 32 * DD);
    for (int s = tid; s < 2048; s += 256) {
      int r = s >> 6, c4 = s & 63;
      *(float4*)&zt[r * 260 + c4 * 4] = zg[s];
    }
  }
  __syncthreads();

  // ---- per-row z2 with exact numpy association ----
  if (tid < 32) z2s[tid] = np_sumsq256(&zt[tid * 260]);
  __syncthreads();

  float z2r[2];
  z2r[0] = z2s[tr];
  z2r[1] = z2s[tr + 16];

  // ---- f32 GEMM screening == full np d computation, track first-min -------
  float m1[2] = {INFINITY, INFINITY};
  int   i1[2] = {0, 0};

  for (int cbk = 0; cbk < 16; cbk++) {
    float acc[2][4];
#pragma unroll
    for (int i = 0; i < 2; i++)
#pragma unroll
      for (int j = 0; j < 4; j++) acc[i][j] = 0.f;

    for (int kc = 0; kc < 8; kc++) {
      const float* cg = cb + (size_t)cbk * 64 * DD + kc * 32;
      for (int s = tid; s < 512; s += 256) {
        int c = s >> 3, ko = (s & 7) * 4;
        *(float4*)&sc[c * 36 + ko] = *(const float4*)(cg + (size_t)c * DD + ko);
      }
      __syncthreads();
#pragma unroll
      for (int k4 = 0; k4 < 8; k4++) {
        float4 A0 = *(const float4*)&zt[(tr     ) * 260 + kc * 32 + k4 * 4];
        float4 A1 = *(const float4*)&zt[(tr + 16) * 260 + kc * 32 + k4 * 4];
        float4 B[4];
        B[0] = *(const float4*)&sc[(tc     ) * 36 + k4 * 4];
        B[1] = *(const float4*)&sc[(tc + 16) * 36 + k4 * 4];
        B[2] = *(const float4*)&sc[(tc + 32) * 36 + k4 * 4];
        B[3] = *(const float4*)&sc[(tc + 48) * 36 + k4 * 4];
        // strict ascending-k f32 FMA chain per (row, code) — BLAS sgemm order
#pragma unroll
        for (int j = 0; j < 4; j++) {
          acc[0][j] = __fmaf_rn(A0.x, B[j].x, acc[0][j]);
          acc[0][j] = __fmaf_rn(A0.y, B[j].y, acc[0][j]);
          acc[0][j] = __fmaf_rn(A0.z, B[j].z, acc[0][j]);
          acc[0][j] = __fmaf_rn(A0.w, B[j].w, acc[0][j]);
          acc[1][j] = __fmaf_rn(A1.x, B[j].x, acc[1][j]);
          acc[1][j] = __fmaf_rn(A1.y, B[j].y, acc[1][j]);
          acc[1][j] = __fmaf_rn(A1.z, B[j].z, acc[1][j]);
          acc[1][j] = __fmaf_rn(A1.w, B[j].w, acc[1][j]);
        }
      }
      __syncthreads();
    }
    // numpy expression rounding: d = fl( fl(z2 - 2*dot) + c2 )
#pragma unroll
    for (int j = 0; j < 4; j++) {
      const int code = cbk * 64 + j * 16 + tc;
      const float c2v = c2n[code];
#pragma unroll
      for (int i = 0; i < 2; i++) {
        const float t1 = 2.0f * acc[i][j];          // exact (x2)
        const float d  = FA(FA(z2r[i], -t1), c2v);
        if (d < m1[i]) { m1[i] = d; i1[i] = code; } // codes ascend: first-min kept
      }
    }
  }

  // ---- cross-thread first-min merge (lexicographic on (d, code)) ----
  float* redm1 = sc;              // [32][16]
  int*   redi1 = (int*)(sc + 512);
#pragma unroll
  for (int i = 0; i < 2; i++) {
    const int r = tr + 16 * i;
    redm1[r * 16 + tc] = m1[i];
    redi1[r * 16 + tc] = i1[i];
  }
  __syncthreads();
  if (tid < 32) {
    float M1 = INFINITY; int I1 = 0x7FFFFFFF;
    for (int q = 0; q < 16; q++) {
      float a = redm1[tid * 16 + q];
      int  ia = redi1[tid * 16 + q];
      if (a < M1 || (a == M1 && ia < I1)) { M1 = a; I1 = ia; }
    }
    rowidx[tid] = I1;
    atomicAdd(&counts[I1], 1);
    out[IDX_OFF + wg * 32 + tid] = (float)I1;
  }
  __syncthreads();

  // ---- gather + zq_st / residual (float32) + loss partial ----
  const int rr  = tid >> 3;       // 0..31 row
  const int seg = tid & 7;        // 0..7  32-element column segment
  const int id  = rowidx[rr];
  const float4* qrow = (const float4*)(cb + (size_t)id * DD + seg * 32);
  const size_t obase = (size_t)(wg * 32 + rr) * DD + seg * 32;
  float ss = 0.f;
#pragma unroll
  for (int u = 0; u < 8; u++) {
    const float4 r4 = *(const float4*)&zt[rr * 260 + seg * 32 + u * 4];
    const float4 q4 = qrow[u];
    float4 stv, rsv;
    float dq;
    stv.x = r4.x + (q4.x - r4.x); rsv.x = r4.x - q4.x; dq = q4.x - r4.x; ss = fmaf(dq, dq, ss);
    stv.y = r4.y + (q4.y - r4.y); rsv.y = r4.y - q4.y; dq = q4.y - r4.y; ss = fmaf(dq, dq, ss);
    stv.z = r4.z + (q4.z - r4.z); rsv.z = r4.z - q4.z; dq = q4.z - r4.z; ss = fmaf(dq, dq, ss);
    stv.w = r4.w + (q4.w - r4.w); rsv.w = r4.w - q4.w; dq = q4.w - r4.w; ss = fmaf(dq, dq, ss);
    *(float4*)(out + ZQ_OFF  + obase + u * 4) = stv;
    *(float4*)(out + RES_OFF + obase + u * 4) = rsv;
  }
  double dss = (double)ss;
  for (int o = 32; o; o >>= 1) dss += __shfl_down(dss, o, 64);
  if ((tid & 63) == 0) wred[tid >> 6] = dss;
  __syncthreads();
  if (tid == 0) bss[wg] = wred[0] + wred[1] + wred[2] + wred[3];
}

// ---------------- K3: scalars (loss, perplexity) ----------------------------
__global__ void vq6_final(const int* __restrict__ counts,
                          const double* __restrict__ bss,
                          float* __restrict__ out) {
  __shared__ double red[256];
  const int t = threadIdx.x;
  double s = 0.0;
  for (int i = t; i < 4096; i += 256) s += bss[i];
  red[t] = s; __syncthreads();
  for (int s2 = 128; s2 > 0; s2 >>= 1) { if (t < s2) red[t] += red[t + s2]; __syncthreads(); }
  const double ssq = red[0];
  __syncthreads();
  double h = 0.0;
  for (int c = t; c < 1024; c += 256) {
    double p = (double)counts[c] / 131072.0;
    h += p * log(p + 1e-10);
  }
  red[t] = h; __syncthreads();
  for (int s2 = 128; s2 > 0; s2 >>= 1) { if (t < s2) red[t] += red[t + s2]; __syncthreads(); }
  if (t == 0) {
    out[LOSS_OFF] = (float)(0.25 * ssq / 33554432.0);
    out[PERP_OFF] = (float)exp(-red[0]);
  }
}

extern "C" void kernel_launch(void* const* d_in, const int* in_sizes, int n_in,
                              void* d_out, int out_size, void* d_ws, size_t ws_size,
                              hipStream_t stream) {
  // Bind inputs by SIZE: z has 33,554,432 elems, codebook 262,144.
  const float* z;
  const float* cb;
  if (in_sizes[0] == NR * DD) { z = (const float*)d_in[0]; cb = (const float*)d_in[1]; }
  else                        { cb = (const float*)d_in[0]; z = (const float*)d_in[1]; }

  float* out = (float*)d_out;
  char* ws = (char*)d_ws;
  int*   counts = (int*)(ws + WS_CNT);
  float* c2n    = (float*)(ws + WS_C2N);
  double* bss   = (double*)(ws + WS_BSS);

  hipMemsetAsync(counts, 0, 4096, stream);
  vq6_c2<<<4, 256, 0, stream>>>(cb, c2n);
  vq6_main<<<NR / 32, 256, 0, stream>>>(z, cb, c2n, out, counts, bss);
  vq6_final<<<1, 256, 0, stream>>>(counts, bss, out);
}

// Round 7
// 1397.385 us; speedup vs baseline: 1.0694x; 1.0694x over previous
//
#include <hip/hip_runtime.h>
#include <math.h>

#define NR 131072
#define KC 1024
#define DD 256

// d_out element offsets (float32 elements)
#define ZQ_OFF  0
#define RES_OFF 33554432
#define IDX_OFF 67108864
#define LOSS_OFF 67239936
#define PERP_OFF 67239937

// ws byte offsets (total ~24.5 KB)
#define WS_CNT 0        // int[1024]
#define WS_C2N 4096     // float[1024]
#define WS_BSS 8192     // double[2048]

#define FM(x,y) __fmul_rn((x),(y))
#define FA(x,y) __fadd_rn((x),(y))

// ---- numpy f32 pairwise sum-of-squares: one 128-block (AVX512 tree) --------
// lane[l] = ((q[l]^2+q[16+l]^2)+(q[32+l]^2+q[48+l]^2))
//         + ((q[64+l]^2+q[80+l]^2)+(q[96+l]^2+q[112+l]^2)); halving 8,4,2,1.
static __device__ __forceinline__ float np_sumsq128(const float* __restrict__ q) {
  float lane[16];
#pragma unroll
  for (int l = 0; l < 16; l++) {
    float s0 = FM(q[l +   0], q[l +   0]);
    float s1 = FM(q[l +  16], q[l +  16]);
    float s2 = FM(q[l +  32], q[l +  32]);
    float s3 = FM(q[l +  48], q[l +  48]);
    float s4 = FM(q[l +  64], q[l +  64]);
    float s5 = FM(q[l +  80], q[l +  80]);
    float s6 = FM(q[l +  96], q[l +  96]);
    float s7 = FM(q[l + 112], q[l + 112]);
    lane[l] = FA(FA(FA(s0, s1), FA(s2, s3)), FA(FA(s4, s5), FA(s6, s7)));
  }
#pragma unroll
  for (int h = 8; h >= 1; h >>= 1)
#pragma unroll
    for (int l = 0; l < 8; l++)
      if (l < h) lane[l] = FA(lane[l], lane[l + h]);
  return lane[0];
}

static __device__ __forceinline__ float np_sumsq256(const float* __restrict__ p) {
  return FA(np_sumsq128(p), np_sumsq128(p + 128));
}

// ---------------- K1: codebook c2 (numpy-replica f32) -----------------------
__global__ void vq7_c2(const float* __restrict__ cb, float* __restrict__ c2n) {
  const int code = blockIdx.x * 256 + threadIdx.x;   // 4 blocks x 256
  if (code < KC) c2n[code] = np_sumsq256(cb + (size_t)code * DD);
}

// ---------------- K2: fused np-f32 argmin + gather + outputs ----------------
// 64 rows/WG, 8 chunks of 128 codes, per-thread 4 rows x 8 codes.
// Bit-exact invariant: each acc[i][j] receives its 256 FMAs in strict
// ascending-k order (kh outer, kc, k4, element inner) == np/BLAS chain.
__global__ __launch_bounds__(256) void vq7_main(
    const float* __restrict__ z, const float* __restrict__ cb,
    const float* __restrict__ c2n,
    float* __restrict__ out, int* __restrict__ counts,
    double* __restrict__ bss) {
  __shared__ __align__(16) float zt[64 * 132];   // 33,792 B: 64 rows x 128k (+4 pad)
  __shared__ __align__(16) float sc[128 * 36];   // 18,432 B: 128 codes x 32k (+4 pad)
  __shared__ float z2b[64][2];
  __shared__ int rowidx[64];
  __shared__ double wred[4];

  const int tid = threadIdx.x;
  const int wg  = blockIdx.x;          // 2048 WGs x 64 rows
  const int tr  = tid >> 4;            // 0..15 -> rows {tr+16i}
  const int tc  = tid & 15;            // 0..15 -> codes {tc+16j} per 128-chunk

  float m1[4]; int i1[4];
#pragma unroll
  for (int i = 0; i < 4; i++) { m1[i] = INFINITY; i1[i] = 0; }

  for (int cbk = 0; cbk < 8; cbk++) {
    float acc[4][8];
#pragma unroll
    for (int i = 0; i < 4; i++)
#pragma unroll
      for (int j = 0; j < 8; j++) acc[i][j] = 0.f;

    for (int kh = 0; kh < 2; kh++) {
      __syncthreads();                 // previous zt readers done
      {
        const size_t zbase = (size_t)wg * 64 * DD + (size_t)kh * 128;
#pragma unroll
        for (int t = 0; t < 8; t++) {
          const int s = tid + 256 * t;
          const int r = s >> 5, c4 = s & 31;
          *(float4*)&zt[r * 132 + c4 * 4] =
              *(const float4*)(z + zbase + (size_t)r * DD + c4 * 4);
        }
      }
      __syncthreads();                 // zt visible
      if (cbk == 0 && tid < 64) z2b[tid][kh] = np_sumsq128(&zt[tid * 132]);

      for (int kc = 0; kc < 4; kc++) {
#pragma unroll
        for (int t = 0; t < 4; t++) {
          const int s = tid + 256 * t;
          const int c = s >> 3, ko = (s & 7) * 4;
          *(float4*)&sc[c * 36 + ko] =
              *(const float4*)(cb + (size_t)(cbk * 128 + c) * DD +
                               kh * 128 + kc * 32 + ko);
        }
        __syncthreads();               // sc visible (also orders z2b vs fold)
#pragma unroll
        for (int k4 = 0; k4 < 8; k4++) {
          float4 A[4], B[8];
#pragma unroll
          for (int i = 0; i < 4; i++)
            A[i] = *(const float4*)&zt[(tr + 16 * i) * 132 + kc * 32 + k4 * 4];
#pragma unroll
          for (int j = 0; j < 8; j++)
            B[j] = *(const float4*)&sc[(tc + 16 * j) * 36 + k4 * 4];
#pragma unroll
          for (int i = 0; i < 4; i++)
#pragma unroll
            for (int j = 0; j < 8; j++) {
              acc[i][j] = __fmaf_rn(A[i].x, B[j].x, acc[i][j]);
              acc[i][j] = __fmaf_rn(A[i].y, B[j].y, acc[i][j]);
              acc[i][j] = __fmaf_rn(A[i].z, B[j].z, acc[i][j]);
              acc[i][j] = __fmaf_rn(A[i].w, B[j].w, acc[i][j]);
            }
        }
        __syncthreads();               // k4 readers done before sc restage
      }
    }

    // fold 128 codes of this chunk: d = fl( fl(z2 - 2*dot) + c2 ), first-min
    float z2v[4];
#pragma unroll
    for (int i = 0; i < 4; i++)
      z2v[i] = FA(z2b[tr + 16 * i][0], z2b[tr + 16 * i][1]);
#pragma unroll
    for (int j = 0; j < 8; j++) {
      const int code = cbk * 128 + j * 16 + tc;
      const float c2v = c2n[code];
#pragma unroll
      for (int i = 0; i < 4; i++) {
        const float t1 = 2.0f * acc[i][j];           // exact (x2)
        const float d  = FA(FA(z2v[i], -t1), c2v);
        if (d < m1[i]) { m1[i] = d; i1[i] = code; }  // ascending codes
      }
    }
  }

  // ---- cross-thread first-min merge (lexicographic on (d, code)) ----
  float* redm1 = sc;                   // [64][16] floats
  int*   redi1 = (int*)(sc + 1024);    // [64][16] ints
#pragma unroll
  for (int i = 0; i < 4; i++) {
    const int r = tr + 16 * i;
    redm1[r * 16 + tc] = m1[i];
    redi1[r * 16 + tc] = i1[i];
  }
  __syncthreads();
  if (tid < 64) {
    float M1 = INFINITY; int I1 = 0x7FFFFFFF;
    for (int q = 0; q < 16; q++) {
      const float a = redm1[tid * 16 + q];
      const int  ia = redi1[tid * 16 + q];
      if (a < M1 || (a == M1 && ia < I1)) { M1 = a; I1 = ia; }
    }
    rowidx[tid] = I1;
    atomicAdd(&counts[I1], 1);
    out[IDX_OFF + wg * 64 + tid] = (float)I1;
  }
  __syncthreads();

  // ---- gather + zq_st / residual (float32) + loss partial ----
  const int rr  = tid >> 2;            // 0..63 row
  const int seg = tid & 3;             // 0..3, 64-float segment
  const int id  = rowidx[rr];
  const size_t zrow = (size_t)(wg * 64 + rr) * DD + seg * 64;
  const float4* zp = (const float4*)(z + zrow);
  const float4* qp = (const float4*)(cb + (size_t)id * DD + seg * 64);
  float ss = 0.f;
#pragma unroll
  for (int u = 0; u < 16; u++) {
    const float4 r4 = zp[u];
    const float4 q4 = qp[u];
    float4 stv, rsv; float dq;
    stv.x = r4.x + (q4.x - r4.x); rsv.x = r4.x - q4.x; dq = q4.x - r4.x; ss = fmaf(dq, dq, ss);
    stv.y = r4.y + (q4.y - r4.y); rsv.y = r4.y - q4.y; dq = q4.y - r4.y; ss = fmaf(dq, dq, ss);
    stv.z = r4.z + (q4.z - r4.z); rsv.z = r4.z - q4.z; dq = q4.z - r4.z; ss = fmaf(dq, dq, ss);
    stv.w = r4.w + (q4.w - r4.w); rsv.w = r4.w - q4.w; dq = q4.w - r4.w; ss = fmaf(dq, dq, ss);
    *(float4*)(out + ZQ_OFF  + zrow + u * 4) = stv;
    *(float4*)(out + RES_OFF + zrow + u * 4) = rsv;
  }
  double dss = (double)ss;
  for (int o = 32; o; o >>= 1) dss += __shfl_down(dss, o, 64);
  if ((tid & 63) == 0) wred[tid >> 6] = dss;
  __syncthreads();
  if (tid == 0) bss[wg] = wred[0] + wred[1] + wred[2] + wred[3];
}

// ---------------- K3: scalars (loss, perplexity) ----------------------------
__global__ void vq7_final(const int* __restrict__ counts,
                          const double* __restrict__ bss,
                          float* __restrict__ out) {
  __shared__ double red[256];
  const int t = threadIdx.x;
  double s = 0.0;
  for (int i = t; i < 2048; i += 256) s += bss[i];
  red[t] = s; __syncthreads();
  for (int s2 = 128; s2 > 0; s2 >>= 1) { if (t < s2) red[t] += red[t + s2]; __syncthreads(); }
  const double ssq = red[0];
  __syncthreads();
  double h = 0.0;
  for (int c = t; c < 1024; c += 256) {
    double p = (double)counts[c] / 131072.0;
    h += p * log(p + 1e-10);
  }
  red[t] = h; __syncthreads();
  for (int s2 = 128; s2 > 0; s2 >>= 1) { if (t < s2) red[t] += red[t + s2]; __syncthreads(); }
  if (t == 0) {
    out[LOSS_OFF] = (float)(0.25 * ssq / 33554432.0);
    out[PERP_OFF] = (float)exp(-red[0]);
  }
}

extern "C" void kernel_launch(void* const* d_in, const int* in_sizes, int n_in,
                              void* d_out, int out_size, void* d_ws, size_t ws_size,
                              hipStream_t stream) {
  // Bind inputs by SIZE: z has 33,554,432 elems, codebook 262,144.
  const float* z;
  const float* cb;
  if (in_sizes[0] == NR * DD) { z = (const float*)d_in[0]; cb = (const float*)d_in[1]; }
  else                        { cb = (const float*)d_in[0]; z = (const float*)d_in[1]; }

  float* out = (float*)d_out;
  char* ws = (char*)d_ws;
  int*    counts = (int*)(ws + WS_CNT);
  float*  c2n    = (float*)(ws + WS_C2N);
  double* bss    = (double*)(ws + WS_BSS);

  hipMemsetAsync(counts, 0, 4096, stream);
  vq7_c2<<<4, 256, 0, stream>>>(cb, c2n);
  vq7_main<<<NR / 64, 256, 0, stream>>>(z, cb, c2n, out, counts, bss);
  vq7_final<<<1, 256, 0, stream>>>(counts, bss, out);
}